// Round 1
// baseline (2541.244 us; speedup 1.0000x reference)
//
#include <hip/hip_runtime.h>
#include <math.h>

#define NN 30000
#define NE 960000
#define HID 256
#define NH 4
#define HD 64

// ---------------------------------------------------------------------------
// Tiled fp32 GEMM with fused epilogues.
// mode 0: C = A@W + bias
// mode 1: C = leaky(gamma*(A@W+bias)*invs + beta2, a)        (encoder, write)
// mode 2: C += leaky(gamma*(A@W+bias)*invs + beta2, a)       (encoder, accumulate)
// ---------------------------------------------------------------------------
#define BM 64
#define BN 64
#define BK 16

__global__ void __launch_bounds__(256) gemm_epi(
    const float* __restrict__ A, const float* __restrict__ W,
    const float* __restrict__ bias,
    const float* __restrict__ gamma, const float* __restrict__ beta2,
    const float* __restrict__ a_ptr,
    float* __restrict__ C, int M, int N, int K, int mode)
{
    __shared__ float As[BK][BM + 4];
    __shared__ float Bs[BK][BN];
    const int bm = blockIdx.y * BM;
    const int bn = blockIdx.x * BN;
    const int t  = threadIdx.x;
    const int tx = t & 15, ty = t >> 4;          // 16x16 thread tile, 4x4 micro
    const int arow  = t >> 2;                    // 0..63
    const int acol4 = (t & 3) << 2;              // 0,4,8,12
    const int brow  = t >> 4;                    // 0..15
    const int bcol4 = (t & 15) << 2;             // 0..60

    float acc[4][4];
#pragma unroll
    for (int i = 0; i < 4; i++)
#pragma unroll
        for (int j = 0; j < 4; j++) acc[i][j] = 0.f;

    for (int k0 = 0; k0 < K; k0 += BK) {
        float4 av = make_float4(0.f, 0.f, 0.f, 0.f);
        const int gr = bm + arow;
        if (gr < M) av = *(const float4*)(A + (size_t)gr * K + k0 + acol4);
        As[acol4 + 0][arow] = av.x;
        As[acol4 + 1][arow] = av.y;
        As[acol4 + 2][arow] = av.z;
        As[acol4 + 3][arow] = av.w;
        const float4 wv = *(const float4*)(W + (size_t)(k0 + brow) * N + bn + bcol4);
        *(float4*)&Bs[brow][bcol4] = wv;
        __syncthreads();
#pragma unroll
        for (int k = 0; k < BK; k++) {
            const float a0 = As[k][ty * 4 + 0];
            const float a1 = As[k][ty * 4 + 1];
            const float a2 = As[k][ty * 4 + 2];
            const float a3 = As[k][ty * 4 + 3];
            const float b0 = Bs[k][tx * 4 + 0];
            const float b1 = Bs[k][tx * 4 + 1];
            const float b2 = Bs[k][tx * 4 + 2];
            const float b3 = Bs[k][tx * 4 + 3];
            acc[0][0] += a0 * b0; acc[0][1] += a0 * b1; acc[0][2] += a0 * b2; acc[0][3] += a0 * b3;
            acc[1][0] += a1 * b0; acc[1][1] += a1 * b1; acc[1][2] += a1 * b2; acc[1][3] += a1 * b3;
            acc[2][0] += a2 * b0; acc[2][1] += a2 * b1; acc[2][2] += a2 * b2; acc[2][3] += a2 * b3;
            acc[3][0] += a3 * b0; acc[3][1] += a3 * b1; acc[3][2] += a3 * b2; acc[3][3] += a3 * b3;
        }
        __syncthreads();
    }

    const int r0 = bm + ty * 4;
    const int c0 = bn + tx * 4;
    const float invs = 1.0f / sqrtf(1.0f + 1e-5f);
    float av_ = 0.f, gm[4], bt[4], bi[4];
#pragma unroll
    for (int j = 0; j < 4; j++) bi[j] = bias[c0 + j];
    if (mode != 0) {
        av_ = *a_ptr;
#pragma unroll
        for (int j = 0; j < 4; j++) { gm[j] = gamma[c0 + j]; bt[j] = beta2[c0 + j]; }
    }
#pragma unroll
    for (int i = 0; i < 4; i++) {
        const int r = r0 + i;
        if (r < M) {
            float vals[4];
#pragma unroll
            for (int j = 0; j < 4; j++) {
                float h = acc[i][j] + bi[j];
                if (mode != 0) {
                    h = gm[j] * h * invs + bt[j];
                    h = (h >= 0.f) ? h : av_ * h;
                }
                vals[j] = h;
            }
            float* cp = C + (size_t)r * N + c0;
            if (mode == 2) {
                float4 prev = *(float4*)cp;
                vals[0] += prev.x; vals[1] += prev.y; vals[2] += prev.z; vals[3] += prev.w;
            }
            *(float4*)cp = make_float4(vals[0], vals[1], vals[2], vals[3]);
        }
    }
}

// ---------------------------------------------------------------------------
// CSR build: count -> deg -> scan -> fill
// ---------------------------------------------------------------------------
__global__ void count_k(const int* __restrict__ dst, int* __restrict__ counts)
{
    const int e = blockIdx.x * 256 + threadIdx.x;
    if (e < NE) atomicAdd(&counts[dst[e]], 1);
}

__global__ void deg_k(const int* __restrict__ counts, float* __restrict__ deg)
{
    const int i = blockIdx.x * 256 + threadIdx.x;
    if (i < NN) deg[i] = fmaxf((float)counts[i], 1.0f);
}

__global__ void __launch_bounds__(1024) scan_k(const int* __restrict__ counts,
                                               int* __restrict__ offs, int n)
{
    __shared__ int buf[1024];
    __shared__ int carry;
    const int t = threadIdx.x;
    if (t == 0) { carry = 0; offs[0] = 0; }
    __syncthreads();
    for (int base = 0; base < n; base += 1024) {
        const int i = base + t;
        int v = (i < n) ? counts[i] : 0;
        buf[t] = v;
        __syncthreads();
        for (int off = 1; off < 1024; off <<= 1) {
            int add = (t >= off) ? buf[t - off] : 0;
            __syncthreads();
            buf[t] += add;
            __syncthreads();
        }
        if (i < n) offs[i + 1] = carry + buf[t];
        __syncthreads();
        if (t == 0) carry += buf[1023];
        __syncthreads();
    }
}

__global__ void fill_k(const int* __restrict__ src, const int* __restrict__ dst,
                       const int* __restrict__ offs, int* __restrict__ cursor,
                       const float* __restrict__ deg,
                       int* __restrict__ csrc, float* __restrict__ cw)
{
    const int e = blockIdx.x * 256 + threadIdx.x;
    if (e < NE) {
        const int d = dst[e];
        const int s = src[e];
        const int p = atomicAdd(&cursor[d], 1);
        const int slot = offs[d] + p;
        csrc[slot] = s;
        cw[slot] = rsqrtf(deg[s] * deg[d]);
    }
}

// ---------------------------------------------------------------------------
// SpMV diffusion step: hout = (alpha*x + beta * A_norm @ hin) * scale
// one block per node, 256 threads = 256 columns
// ---------------------------------------------------------------------------
__global__ void __launch_bounds__(256) spmv_k(
    const float* __restrict__ hin, const float* __restrict__ x,
    const int* __restrict__ offs, const int* __restrict__ csrc,
    const float* __restrict__ cw, float* __restrict__ hout, float scale)
{
    const int node = blockIdx.x;
    const int t = threadIdx.x;
    const int start = offs[node], end = offs[node + 1];
    __shared__ int   ss[256];
    __shared__ float sw[256];
    float acc = 0.f;
    for (int base = start; base < end; base += 256) {
        const int cnt = min(256, end - base);
        __syncthreads();
        if (t < cnt) { ss[t] = csrc[base + t]; sw[t] = cw[base + t]; }
        __syncthreads();
#pragma unroll 4
        for (int j = 0; j < cnt; j++)
            acc += hin[(size_t)ss[j] * HID + t] * sw[j];
    }
    const size_t o = (size_t)node * HID + t;
    hout[o] = (0.1f * x[o] + 0.9f * acc) * scale;
}

// ---------------------------------------------------------------------------
// Precompute Wvo[k][h*256+j] = sum_d Wv[k][64h+d]*Wo[64h+d][j]
// and bvo[h*256+j] = sum_d bv[64h+d]*Wo[64h+d][j]
// ---------------------------------------------------------------------------
__global__ void build_wvo(const float* __restrict__ Wv, const float* __restrict__ Wo,
                          const float* __restrict__ bv,
                          float* __restrict__ Wvo, float* __restrict__ bvo)
{
    const int gid = blockIdx.x * 256 + threadIdx.x;
    if (gid < 256 * 1024) {
        const int k = gid >> 10;
        const int col = gid & 1023;
        const int h = col >> 8, j = col & 255;
        float s = 0.f;
#pragma unroll 8
        for (int d = 0; d < HD; d++)
            s += Wv[k * HID + h * HD + d] * Wo[(h * HD + d) * HID + j];
        Wvo[(size_t)k * 1024 + col] = s;
    } else if (gid < 256 * 1024 + 1024) {
        const int col = gid - 256 * 1024;
        const int h = col >> 8, j = col & 255;
        float s = 0.f;
#pragma unroll 8
        for (int d = 0; d < HD; d++)
            s += bv[h * HD + d] * Wo[(h * HD + d) * HID + j];
        bvo[col] = s;
    }
}

// ---------------------------------------------------------------------------
// Fused attention: per node, gather Cq/Ck rows, softmax(QK^T/8),
// z = attn @ P_gathered + bo + mem ; also emits final_h and logits.
// ---------------------------------------------------------------------------
__global__ void __launch_bounds__(256) attn_k(
    const float* __restrict__ Cq, const float* __restrict__ Ck,
    const float* __restrict__ P, const float* __restrict__ comb,
    const int* __restrict__ midx, const float* __restrict__ bo,
    const float* __restrict__ Wc, const float* __restrict__ bc,
    float* __restrict__ zout, float* __restrict__ fhout, float* __restrict__ lout)
{
    __shared__ float qs[16][260];     // +4 pad breaks 256-stride bank conflicts
    __shared__ float ks[16][260];
    __shared__ float at[NH][16][16];
    __shared__ float row0[256];
    __shared__ int   idx[16];
    const int n = blockIdx.x;
    const int t = threadIdx.x;

    if (t < 16) idx[t] = (t == 0) ? n : midx[n * 15 + t - 1];
    __syncthreads();
#pragma unroll
    for (int r = 0; r < 16; r++) {
        const size_t g = (size_t)idx[r] * HID + t;
        qs[r][t] = Cq[g];
        ks[r][t] = Ck[g];
    }
    __syncthreads();

    const int kr = t & 15, qr = t >> 4;   // 256 threads = 16 q-rows x 16 k-rows
#pragma unroll
    for (int h = 0; h < NH; h++) {
        float s = 0.f;
#pragma unroll
        for (int i = 0; i < HD; i++)
            s += qs[qr][h * HD + i] * ks[kr][h * HD + i];
        s *= 0.125f;                       // 1/sqrt(64)
        float m = s;
        m = fmaxf(m, __shfl_xor(m, 1));
        m = fmaxf(m, __shfl_xor(m, 2));
        m = fmaxf(m, __shfl_xor(m, 4));
        m = fmaxf(m, __shfl_xor(m, 8));
        const float e = __expf(s - m);
        float sum = e;
        sum += __shfl_xor(sum, 1);
        sum += __shfl_xor(sum, 2);
        sum += __shfl_xor(sum, 4);
        sum += __shfl_xor(sum, 8);
        at[h][qr][kr] = e / sum;
    }
    __syncthreads();

    // output: thread t = column c; acc over 16 k-rows x 4 heads of P
    float acc[16];
#pragma unroll
    for (int q2 = 0; q2 < 16; q2++) acc[q2] = 0.f;
    for (int k2 = 0; k2 < 16; k2++) {
        const size_t base = (size_t)idx[k2] * 1024;
        const float p0 = P[base + t];
        const float p1 = P[base + 256 + t];
        const float p2 = P[base + 512 + t];
        const float p3 = P[base + 768 + t];
#pragma unroll
        for (int q2 = 0; q2 < 16; q2++) {
            acc[q2] += at[0][q2][k2] * p0 + at[1][q2][k2] * p1
                     + at[2][q2][k2] * p2 + at[3][q2][k2] * p3;
        }
    }
    const float bov = bo[t];
#pragma unroll
    for (int q2 = 0; q2 < 16; q2++) {
        const float val = acc[q2] + bov + comb[(size_t)idx[q2] * HID + t];
        zout[((size_t)n * 16 + q2) * HID + t] = val;
        if (q2 == 0) { row0[t] = val; fhout[(size_t)n * HID + t] = val; }
    }
    __syncthreads();
    if (t < 40) {
        float s = bc[t];
#pragma unroll 8
        for (int c = 0; c < 256; c++) s += row0[c] * Wc[c * 40 + t];
        lout[(size_t)n * 40 + t] = s;
    }
}

// ---------------------------------------------------------------------------
extern "C" void kernel_launch(void* const* d_in, const int* in_sizes, int n_in,
                              void* d_out, int out_size, void* d_ws, size_t ws_size,
                              hipStream_t stream)
{
    const float* text = (const float*)d_in[0];
    const float* vis  = (const float*)d_in[1];
    const int*   eidx = (const int*)d_in[2];
    const int*   midx = (const int*)d_in[3];
    const float* tW = (const float*)d_in[4];
    const float* tb = (const float*)d_in[5];
    const float* tg = (const float*)d_in[6];
    const float* tbe = (const float*)d_in[7];
    const float* ta = (const float*)d_in[8];
    const float* vW = (const float*)d_in[9];
    const float* vb = (const float*)d_in[10];
    const float* vg = (const float*)d_in[11];
    const float* vbe = (const float*)d_in[12];
    const float* va = (const float*)d_in[13];
    const float* Wq = (const float*)d_in[14];
    const float* bq = (const float*)d_in[15];
    const float* Wk = (const float*)d_in[16];
    const float* bk = (const float*)d_in[17];
    const float* Wv = (const float*)d_in[18];
    const float* bv = (const float*)d_in[19];
    const float* Wo = (const float*)d_in[20];
    const float* bo = (const float*)d_in[21];
    const float* Wc = (const float*)d_in[22];
    const float* bc = (const float*)d_in[23];

    float* out_logits = (float*)d_out;
    float* out_fh = out_logits + (size_t)NN * 40;
    float* out_z  = out_fh + (size_t)NN * HID;

    // workspace carve (~286 MB)
    const size_t SLOT = (size_t)NN * HID;
    float* s_x   = (float*)d_ws;
    float* s_h1  = s_x + SLOT;
    float* s_h2  = s_h1 + SLOT;
    float* s_cq  = s_h2 + SLOT;
    float* s_ck  = s_cq + SLOT;
    float* s_P   = s_ck + SLOT;                 // NN x 1024
    float* s_wvo = s_P + (size_t)NN * 1024;     // 256 x 1024
    float* s_bvo = s_wvo + 256 * 1024;          // 1024
    float* c_deg = s_bvo + 1024;                // NN floats
    int* c_counts = (int*)(c_deg + NN);
    int* c_off    = c_counts + NN;              // NN+1
    int* c_cursor = c_off + (NN + 1);
    int* c_src    = c_cursor + NN;              // NE
    float* c_w    = (float*)(c_src + NE);       // NE

    const int* e_src = eidx;
    const int* e_dst = eidx + NE;

    hipMemsetAsync(c_counts, 0, NN * sizeof(int), stream);
    hipMemsetAsync(c_cursor, 0, NN * sizeof(int), stream);

    const dim3 gEnc(HID / BN, (NN + BM - 1) / BM);

    // encoders: x = leaky_bn(text@tW) + leaky_bn(vis@vW)
    gemm_epi<<<gEnc, 256, 0, stream>>>(text, tW, tb, tg, tbe, ta, s_x, NN, HID, 768, 1);
    gemm_epi<<<gEnc, 256, 0, stream>>>(vis,  vW, vb, vg, vbe, va, s_x, NN, HID, 512, 2);

    // CSR build
    count_k<<<NE / 256, 256, 0, stream>>>(e_dst, c_counts);
    deg_k<<<(NN + 255) / 256, 256, 0, stream>>>(c_counts, c_deg);
    scan_k<<<1, 1024, 0, stream>>>(c_counts, c_off, NN);
    fill_k<<<NE / 256, 256, 0, stream>>>(e_src, e_dst, c_off, c_cursor, c_deg, c_src, c_w);

    // diffusion: linear => single pass on (enc_t + enc_v); z == 1.0 for these consts
    const double beta_k = 0.9 * 0.9 * 0.9 * 0.9;
    const double zd = 0.1 * (1.0 - beta_k) / (1.0 - 0.9) + beta_k;
    const float invz = (float)(1.0 / zd);
    spmv_k<<<NN, 256, 0, stream>>>(s_x,  s_x, c_off, c_src, c_w, s_h1, 1.0f);
    spmv_k<<<NN, 256, 0, stream>>>(s_h1, s_x, c_off, c_src, c_w, s_h2, 1.0f);
    spmv_k<<<NN, 256, 0, stream>>>(s_h2, s_x, c_off, c_src, c_w, s_h1, 1.0f);
    spmv_k<<<NN, 256, 0, stream>>>(s_h1, s_x, c_off, c_src, c_w, s_h2, invz); // s_h2 = combined

    // MHA projections on combined; P folds Wv@Wo per head
    build_wvo<<<(256 * 1024 + 1024) / 256, 256, 0, stream>>>(Wv, Wo, bv, s_wvo, s_bvo);
    gemm_epi<<<gEnc, 256, 0, stream>>>(s_h2, Wq, bq, nullptr, nullptr, nullptr, s_cq, NN, HID, HID, 0);
    gemm_epi<<<gEnc, 256, 0, stream>>>(s_h2, Wk, bk, nullptr, nullptr, nullptr, s_ck, NN, HID, HID, 0);
    const dim3 gP(1024 / BN, (NN + BM - 1) / BM);
    gemm_epi<<<gP, 256, 0, stream>>>(s_h2, s_wvo, s_bvo, nullptr, nullptr, nullptr, s_P, NN, 1024, HID, 0);

    // fused attention + epilogue + logits
    attn_k<<<NN, 256, 0, stream>>>(s_cq, s_ck, s_P, s_h2, midx, bo, Wc, bc,
                                   out_z, out_fh, out_logits);
}